// Round 2
// baseline (326.047 us; speedup 1.0000x reference)
//
#include <hip/hip_runtime.h>

// DynamicHead: varying-coefficient MLP.
//   basis(t) in R^12; layer: out[b,o] = sum_s basis[b,s]*( sum_i x[b,i]*W[s,i,o] + bias[s,o] )
// R2: block 64 rows x 256 cols (full N), 4 waves of 64x64 (m_frags=4 halves L2 B traffic
// vs R1), grid 512 = exactly 2 blocks/CU. A+B software prefetch distance 1. Per-s
// accumulator scaled into out_acc (basis/bias only touched in epilogue).

typedef __attribute__((ext_vector_type(8))) short short8;
typedef __attribute__((ext_vector_type(4))) float floatx4;

#define XPAD 264  // 256 + 8 shorts pad -> row stride 528 B

__device__ __forceinline__ short f2bf(float f){
  unsigned u = __float_as_uint(f);
  u = u + 0x7fffu + ((u >> 16) & 1u);   // RNE
  return (short)(u >> 16);
}
__device__ __forceinline__ float bf2f(short s){
  return __uint_as_float(((unsigned)(unsigned short)s) << 16);
}

__device__ __forceinline__ void make_basis(float t, float* p){
  p[0] = 1.f; p[1] = t; p[2] = t*t; p[3] = p[2]*t;
  const float knots[8] = {1.f/9.f, 2.f/9.f, 3.f/9.f, 4.f/9.f,
                          5.f/9.f, 6.f/9.f, 7.f/9.f, 8.f/9.f};
  #pragma unroll
  for (int j = 0; j < 8; ++j){
    float d = t - knots[j];
    d = fmaxf(d, 0.f);
    p[4+j] = d*d*d;
  }
}

// Pack W (12,256,256) fp32 -> bf16 MFMA-B-frag order, coalesced via LDS transpose.
// Wp element ((s*8+ko)*16+ntg)*512 + (q*16+n16)*8 + j = bf16(W[s][ko*32+q*8+j][ntg*16+n16])
// One block per (layer, s*8+ko) chunk: 192 blocks.
__global__ __launch_bounds__(256)
void pack_w_kernel(const float* __restrict__ W0, const float* __restrict__ W1,
                   short* __restrict__ Wp0, short* __restrict__ Wp1){
  __shared__ float wl[32 * 260];
  const int blk = blockIdx.x;
  const float* W = (blk < 96) ? W0 : W1;
  short* Wp      = (blk < 96) ? Wp0 : Wp1;
  const int c    = (blk < 96) ? blk : blk - 96;   // s*8+ko
  const int tid  = threadIdx.x;
  const float* src = W + (size_t)c * 8192;        // rows ko*32..+32, all 256 cols
  #pragma unroll
  for (int it = 0; it < 8; ++it){
    int idx = it * 256 + tid;          // float4 index, 0..2047
    int r = idx >> 6, c4 = idx & 63;
    float4 v = *(const float4*)(src + (size_t)idx * 4);
    float* d = &wl[r * 260 + c4 * 4];
    d[0] = v.x; d[1] = v.y; d[2] = v.z; d[3] = v.w;
  }
  __syncthreads();
  short* dst = Wp + (size_t)c * 8192;
  #pragma unroll
  for (int w = 0; w < 4; ++w){
    int v = w * 256 + tid;             // 0..1023
    int n16 = v & 15, qq = (v >> 4) & 3, ntg = v >> 6;
    short8 o;
    #pragma unroll
    for (int j = 0; j < 8; ++j)
      o[j] = f2bf(wl[(qq * 8 + j) * 260 + ntg * 16 + n16]);
    *(short8*)(dst + (size_t)v * 8) = o;
  }
}

// Block: 64 rows x 256 cols, 4 waves each 64x64 (4 m-frags x 4 n-frags).
// Grid: 512 blocks -> exactly 2 blocks/CU.
template<bool IN_F32>
__global__ __launch_bounds__(256, 2)
void layer_kernel(const void* __restrict__ in_v, const float* __restrict__ treat,
                  const short* __restrict__ Wp, const float* __restrict__ bias,
                  short* __restrict__ out){
  __shared__ short Xlds[64 * XPAD];   // 33792 B
  __shared__ float blds[12 * 64];     // basis [s][m]

  const int tid  = threadIdx.x;
  const int m0   = blockIdx.x * 64;
  const int lane = tid & 63;
  const int wid  = tid >> 6;          // wave -> cols [wid*64, wid*64+64)
  const int q    = lane >> 4;
  const int l16  = lane & 15;

  // ---- stage X tile (64 x 256) into LDS as bf16 ----
  if (IN_F32){
    const float* X = (const float*)in_v;
    #pragma unroll
    for (int it = 0; it < 16; ++it){
      int idx = it * 256 + tid;        // 4096 float4 chunks
      int m = idx >> 6, c = idx & 63;
      float4 v = *(const float4*)(X + (size_t)(m0 + m) * 256 + c * 4);
      short4 sv;
      sv.x = f2bf(v.x); sv.y = f2bf(v.y); sv.z = f2bf(v.z); sv.w = f2bf(v.w);
      *(short4*)&Xlds[m * XPAD + c * 4] = sv;
    }
  } else {
    const short* X = (const short*)in_v;
    #pragma unroll
    for (int it = 0; it < 8; ++it){
      int idx = it * 256 + tid;        // 2048 short8 chunks
      int m = idx >> 5, c = idx & 31;
      short8 v = *(const short8*)(X + (size_t)(m0 + m) * 256 + c * 8);
      *(short8*)&Xlds[m * XPAD + c * 8] = v;
    }
  }
  if (tid < 64){
    float t = treat[m0 + tid];
    float p[12]; make_basis(t, p);
    #pragma unroll
    for (int s = 0; s < 12; ++s) blds[s * 64 + tid] = p[s];
  }
  __syncthreads();

  // b-frag base: ntg = wid*4 + nt; addr = s*65536 + ko*8192 + ntg*512 + lane*8
  const short* wb = Wp + (size_t)(wid * 4) * 512 + lane * 8;

  const floatx4 zero = {0.f, 0.f, 0.f, 0.f};
  floatx4 out_acc[4][4];
  #pragma unroll
  for (int mt = 0; mt < 4; ++mt)
    #pragma unroll
    for (int nt = 0; nt < 4; ++nt) out_acc[mt][nt] = zero;

  short8 ac[4], an[4], bc[4], bn[4];
  #pragma unroll
  for (int mt = 0; mt < 4; ++mt)
    ac[mt] = *(const short8*)&Xlds[(mt * 16 + l16) * XPAD + q * 8];
  #pragma unroll
  for (int nt = 0; nt < 4; ++nt)
    bc[nt] = *(const short8*)(wb + nt * 512);

  for (int s = 0; s < 12; ++s){
    // bias for this s (epilogue-only use; long latency budget)
    float bv[4];
    #pragma unroll
    for (int nt = 0; nt < 4; ++nt)
      bv[nt] = bias[s * 256 + wid * 64 + nt * 16 + l16];

    floatx4 acc[4][4];
    #pragma unroll
    for (int mt = 0; mt < 4; ++mt)
      #pragma unroll
      for (int nt = 0; nt < 4; ++nt) acc[mt][nt] = zero;

    #pragma unroll
    for (int ko = 0; ko < 8; ++ko){
      const bool more = (ko < 7) || (s < 11);
      if (more){
        const int ko_n = (ko + 1) & 7;
        #pragma unroll
        for (int mt = 0; mt < 4; ++mt)
          an[mt] = *(const short8*)&Xlds[(mt * 16 + l16) * XPAD + ko_n * 32 + q * 8];
        const short* wb_n = wb + (size_t)(s + (ko == 7 ? 1 : 0)) * 65536 + ko_n * 8192;
        #pragma unroll
        for (int nt = 0; nt < 4; ++nt)
          bn[nt] = *(const short8*)(wb_n + nt * 512);
      }
      #pragma unroll
      for (int mt = 0; mt < 4; ++mt)
        #pragma unroll
        for (int nt = 0; nt < 4; ++nt)
          acc[mt][nt] = __builtin_amdgcn_mfma_f32_16x16x32_bf16(
              ac[mt], bc[nt], acc[mt][nt], 0, 0, 0);
      if (more){
        #pragma unroll
        for (int mt = 0; mt < 4; ++mt) ac[mt] = an[mt];
        #pragma unroll
        for (int nt = 0; nt < 4; ++nt) bc[nt] = bn[nt];
      }
    }

    // out_acc += basis_s * (acc + bias_s)
    floatx4 bas[4];
    #pragma unroll
    for (int mt = 0; mt < 4; ++mt)
      bas[mt] = *(const floatx4*)&blds[s * 64 + mt * 16 + q * 4];
    #pragma unroll
    for (int mt = 0; mt < 4; ++mt)
      #pragma unroll
      for (int nt = 0; nt < 4; ++nt)
        #pragma unroll
        for (int r = 0; r < 4; ++r)
          out_acc[mt][nt][r] += bas[mt][r] * (acc[mt][nt][r] + bv[nt]);
  }

  // epilogue: relu + bf16 store. C/D: col=lane&15, row=(lane>>4)*4+reg.
  #pragma unroll
  for (int mt = 0; mt < 4; ++mt){
    #pragma unroll
    for (int nt = 0; nt < 4; ++nt){
      int col = wid * 64 + nt * 16 + l16;
      #pragma unroll
      for (int r = 0; r < 4; ++r){
        int row = m0 + mt * 16 + q * 4 + r;
        float vv = fmaxf(out_acc[mt][nt][r], 0.f);
        out[(size_t)row * 256 + col] = f2bf(vv);
      }
    }
  }
}

// Final layer (out dim 1): one wave per 4 rows, W2 staged in LDS. 2048 blocks.
__global__ __launch_bounds__(256)
void final_kernel(const short* __restrict__ X2, const float* __restrict__ treat,
                  const float* __restrict__ W2, const float* __restrict__ b2,
                  float* __restrict__ out){
  __shared__ float w2l[12 * 256];
  __shared__ float b2l[12];
  const int tid = threadIdx.x;
  const int m0 = blockIdx.x * 16;
  #pragma unroll
  for (int it = 0; it < 12; ++it) w2l[it * 256 + tid] = W2[it * 256 + tid];
  if (tid < 12) b2l[tid] = b2[tid];
  __syncthreads();
  const int lane = tid & 63, wid = tid >> 6;
  #pragma unroll
  for (int rr = 0; rr < 4; ++rr){
    int b = m0 + wid * 4 + rr;
    float t = treat[b];
    float p[12]; make_basis(t, p);
    const short* xr = X2 + (size_t)b * 256 + lane * 4;
    short4 xv = *(const short4*)xr;
    float xs[4] = { bf2f(xv.x), bf2f(xv.y), bf2f(xv.z), bf2f(xv.w) };
    float ws[4] = {0.f, 0.f, 0.f, 0.f};
    #pragma unroll
    for (int s = 0; s < 12; ++s){
      floatx4 w4 = *(const floatx4*)&w2l[s * 256 + lane * 4];
      #pragma unroll
      for (int j = 0; j < 4; ++j) ws[j] += p[s] * w4[j];
    }
    float dot = xs[0]*ws[0] + xs[1]*ws[1] + xs[2]*ws[2] + xs[3]*ws[3];
    #pragma unroll
    for (int off = 32; off > 0; off >>= 1) dot += __shfl_down(dot, off, 64);
    if (lane == 0){
      float bb = 0.f;
      #pragma unroll
      for (int s = 0; s < 12; ++s) bb += p[s] * b2l[s];
      out[b] = dot + bb;
    }
  }
}

extern "C" void kernel_launch(void* const* d_in, const int* in_sizes, int n_in,
                              void* d_out, int out_size, void* d_ws, size_t ws_size,
                              hipStream_t stream){
  const float* treat = (const float*)d_in[0];
  const float* feat  = (const float*)d_in[1];
  const float* W0    = (const float*)d_in[2];
  const float* b0    = (const float*)d_in[3];
  const float* W1    = (const float*)d_in[4];
  const float* b1    = (const float*)d_in[5];
  const float* W2    = (const float*)d_in[6];
  const float* b2    = (const float*)d_in[7];

  char* ws = (char*)d_ws;
  short* Wp0 = (short*)(ws);                     // 1,572,864 B
  short* Wp1 = (short*)(ws + 1572864);           // 1,572,864 B
  short* X1  = (short*)(ws + 3145728);           // 16,777,216 B
  short* X2  = (short*)(ws + 19922944);          // 16,777,216 B
  float* out = (float*)d_out;

  pack_w_kernel<<<192, 256, 0, stream>>>(W0, W1, Wp0, Wp1);
  layer_kernel<true ><<<512, 256, 0, stream>>>((const void*)feat, treat, Wp0, b0, X1);
  layer_kernel<false><<<512, 256, 0, stream>>>((const void*)X1,  treat, Wp1, b1, X2);
  final_kernel<<<2048, 256, 0, stream>>>(X2, treat, W2, b2, out);
}

// Round 3
// 203.514 us; speedup vs baseline: 1.6021x; 1.6021x over previous
//
#include <hip/hip_runtime.h>

// DynamicHead: varying-coefficient MLP, R3 = flat fp16 GEMM.
//   out[m,o] = sum_{s,i} (bas_s[m]*x[m,i]) * W[s,i,o] + sum_s bas_s[m]*b[s,o]
// Basis folded into A-frags on the fly (v_pk_mul_f16), single fp32 accumulator,
// B pre-packed in MFMA-frag order read straight from L2 (no per-kstep barriers),
// block = 128 rows x 256 cols (8 waves of 64x64) -> B traffic/CU ~26 B/cyc distinct.

typedef __attribute__((ext_vector_type(8))) _Float16 half8;
typedef __attribute__((ext_vector_type(4))) _Float16 half4;
typedef __attribute__((ext_vector_type(4))) float floatx4;

#define XPAD 264  // halves per LDS row: 256 + 8

__device__ __forceinline__ void make_basis(float t, float* p){
  p[0] = 1.f; p[1] = t; p[2] = t*t; p[3] = p[2]*t;
  const float knots[8] = {1.f/9.f, 2.f/9.f, 3.f/9.f, 4.f/9.f,
                          5.f/9.f, 6.f/9.f, 7.f/9.f, 8.f/9.f};
  #pragma unroll
  for (int j = 0; j < 8; ++j){
    float d = t - knots[j];
    d = fmaxf(d, 0.f);
    p[4+j] = d*d*d;
  }
}

// Pack W (12,256,256) fp32 -> f16 MFMA-B-frag order via LDS transpose.
// Wp[(κ*16+ntg)*512 + (q*16+n16)*8 + j] = f16(W[κ/8][(κ%8)*32+q*8+j][ntg*16+n16]),
// κ = s*8+ko in 0..95. One block per (layer, κ): 192 blocks.
__global__ __launch_bounds__(256)
void pack_w_kernel(const float* __restrict__ W0, const float* __restrict__ W1,
                   _Float16* __restrict__ Wp0, _Float16* __restrict__ Wp1){
  __shared__ float wl[32 * 260];
  const int blk = blockIdx.x;
  const float* W = (blk < 96) ? W0 : W1;
  _Float16* Wp   = (blk < 96) ? Wp0 : Wp1;
  const int c    = (blk < 96) ? blk : blk - 96;   // κ
  const int tid  = threadIdx.x;
  const float* src = W + (size_t)c * 8192;        // 32 k-rows x 256 cols
  #pragma unroll
  for (int it = 0; it < 8; ++it){
    int idx = it * 256 + tid;          // float4 index 0..2047
    int r = idx >> 6, c4 = idx & 63;
    float4 v = *(const float4*)(src + (size_t)idx * 4);
    float* d = &wl[r * 260 + c4 * 4];
    d[0] = v.x; d[1] = v.y; d[2] = v.z; d[3] = v.w;
  }
  __syncthreads();
  _Float16* dst = Wp + (size_t)c * 8192;
  #pragma unroll
  for (int w = 0; w < 4; ++w){
    int v = w * 256 + tid;             // 0..1023
    int n16 = v & 15, qq = (v >> 4) & 3, ntg = v >> 6;
    half8 o;
    #pragma unroll
    for (int j = 0; j < 8; ++j)
      o[j] = (_Float16)wl[(qq * 8 + j) * 260 + ntg * 16 + n16];
    *(half8*)(dst + (size_t)v * 8) = o;
  }
}

// Block: 128 rows x 256 cols, 512 threads = 8 waves as 2(m) x 4(n) of 64x64.
// Grid: 256 blocks -> 1 block/CU. Single barrier (X stage); K-loop barrier-free.
template<bool IN_F32>
__global__ __launch_bounds__(512, 2)
void layer_kernel(const void* __restrict__ in_v, const float* __restrict__ treat,
                  const _Float16* __restrict__ Wp, const float* __restrict__ bias,
                  _Float16* __restrict__ out){
  __shared__ _Float16 Xl[128 * XPAD];   // 67,584 B
  __shared__ float blds[12 * 128];      // 6,144 B

  const int tid  = threadIdx.x;
  const int m0   = blockIdx.x * 128;
  const int lane = tid & 63;
  const int wid  = tid >> 6;
  const int wm   = wid >> 2;            // 0..1: rows wm*64..+64
  const int wn   = wid & 3;             // 0..3: cols wn*64..+64
  const int q    = lane >> 4;
  const int l16  = lane & 15;

  // ---- stage X tile (128 x 256) into LDS as f16 ----
  if (IN_F32){
    const float* X = (const float*)in_v;
    #pragma unroll
    for (int it = 0; it < 16; ++it){
      int idx = it * 512 + tid;          // 8192 float4 chunks
      int m = idx >> 6, c = idx & 63;
      float4 v = *(const float4*)(X + (size_t)(m0 + m) * 256 + c * 4);
      half4 h = { (_Float16)v.x, (_Float16)v.y, (_Float16)v.z, (_Float16)v.w };
      *(half4*)&Xl[m * XPAD + c * 4] = h;
    }
  } else {
    const _Float16* X = (const _Float16*)in_v;
    #pragma unroll
    for (int it = 0; it < 8; ++it){
      int idx = it * 512 + tid;          // 4096 half8 chunks
      int m = idx >> 5, c = idx & 31;
      half8 v = *(const half8*)(X + (size_t)(m0 + m) * 256 + c * 8);
      *(half8*)&Xl[m * XPAD + c * 8] = v;
    }
  }
  if (tid < 128){
    float t = treat[m0 + tid];
    float p[12]; make_basis(t, p);
    #pragma unroll
    for (int s = 0; s < 12; ++s) blds[s * 128 + tid] = p[s];
  }
  __syncthreads();

  // A frag: row = wm*64 + mt*16 + l16, k = ko*32 + q*8 + j (halves in Xl)
  const unsigned xbase = (unsigned)(wm * 64 + l16) * XPAD + q * 8;
  // B frag: linear kappa stream, frag base advances 8192 halves per kstep
  const _Float16* wb = Wp + wn * 2048 + lane * 8;

  const floatx4 zero = {0.f, 0.f, 0.f, 0.f};
  floatx4 acc[4][4];
  #pragma unroll
  for (int mt = 0; mt < 4; ++mt)
    #pragma unroll
    for (int nt = 0; nt < 4; ++nt) acc[mt][nt] = zero;

  half8 xc[4], xn[4], bc[4], bn[4];
  #pragma unroll
  for (int mt = 0; mt < 4; ++mt)
    xc[mt] = *(const half8*)&Xl[xbase + mt * 16 * XPAD];
  #pragma unroll
  for (int nt = 0; nt < 4; ++nt)
    bc[nt] = *(const half8*)(wb + nt * 512);
  wb += 8192;

  for (int s = 0; s < 12; ++s){
    _Float16 bash[4];
    #pragma unroll
    for (int mt = 0; mt < 4; ++mt)
      bash[mt] = (_Float16)blds[s * 128 + wm * 64 + mt * 16 + l16];

    #pragma unroll
    for (int ko = 0; ko < 8; ++ko){
      const bool more = (s < 11) || (ko < 7);
      if (more){
        const int ko_n = (ko + 1) & 7;
        #pragma unroll
        for (int mt = 0; mt < 4; ++mt)
          xn[mt] = *(const half8*)&Xl[xbase + mt * 16 * XPAD + ko_n * 32];
        #pragma unroll
        for (int nt = 0; nt < 4; ++nt)
          bn[nt] = *(const half8*)(wb + nt * 512);
      }
      // apply basis to A (v_pk_mul_f16), then MFMA
      half8 az[4];
      #pragma unroll
      for (int mt = 0; mt < 4; ++mt) az[mt] = xc[mt] * bash[mt];
      #pragma unroll
      for (int mt = 0; mt < 4; ++mt)
        #pragma unroll
        for (int nt = 0; nt < 4; ++nt)
          acc[mt][nt] = __builtin_amdgcn_mfma_f32_16x16x32_f16(
              az[mt], bc[nt], acc[mt][nt], 0, 0, 0);
      if (more){
        #pragma unroll
        for (int mt = 0; mt < 4; ++mt) xc[mt] = xn[mt];
        #pragma unroll
        for (int nt = 0; nt < 4; ++nt) bc[nt] = bn[nt];
        wb += 8192;
      }
    }
  }

  // ---- epilogue: + sum_s bas_s*b[s,o], relu, f16 store ----
  for (int s = 0; s < 12; ++s){
    float bl[4];
    #pragma unroll
    for (int nt = 0; nt < 4; ++nt)
      bl[nt] = bias[s * 256 + wn * 64 + nt * 16 + l16];
    floatx4 bs[4];
    #pragma unroll
    for (int mt = 0; mt < 4; ++mt)
      bs[mt] = *(const floatx4*)&blds[s * 128 + wm * 64 + mt * 16 + q * 4];
    #pragma unroll
    for (int mt = 0; mt < 4; ++mt)
      #pragma unroll
      for (int nt = 0; nt < 4; ++nt)
        #pragma unroll
        for (int r = 0; r < 4; ++r)
          acc[mt][nt][r] += bs[mt][r] * bl[nt];
  }
  // C/D layout: col = lane&15, row = (lane>>4)*4 + reg
  #pragma unroll
  for (int mt = 0; mt < 4; ++mt){
    #pragma unroll
    for (int nt = 0; nt < 4; ++nt){
      int col = wn * 64 + nt * 16 + l16;
      #pragma unroll
      for (int r = 0; r < 4; ++r){
        int row = m0 + wm * 64 + mt * 16 + q * 4 + r;
        out[(size_t)row * 256 + col] = (_Float16)fmaxf(acc[mt][nt][r], 0.f);
      }
    }
  }
}

// Final layer (out dim 1): one wave per 4 rows, W2 staged in LDS. 2048 blocks.
__global__ __launch_bounds__(256)
void final_kernel(const _Float16* __restrict__ X2, const float* __restrict__ treat,
                  const float* __restrict__ W2, const float* __restrict__ b2,
                  float* __restrict__ out){
  __shared__ float w2l[12 * 256];
  __shared__ float b2l[12];
  const int tid = threadIdx.x;
  const int m0 = blockIdx.x * 16;
  #pragma unroll
  for (int it = 0; it < 12; ++it) w2l[it * 256 + tid] = W2[it * 256 + tid];
  if (tid < 12) b2l[tid] = b2[tid];
  __syncthreads();
  const int lane = tid & 63, wid = tid >> 6;
  #pragma unroll
  for (int rr = 0; rr < 4; ++rr){
    int b = m0 + wid * 4 + rr;
    float t = treat[b];
    float p[12]; make_basis(t, p);
    half4 xv = *(const half4*)(X2 + (size_t)b * 256 + lane * 4);
    float xs[4] = { (float)xv.x, (float)xv.y, (float)xv.z, (float)xv.w };
    float ws[4] = {0.f, 0.f, 0.f, 0.f};
    #pragma unroll
    for (int s = 0; s < 12; ++s){
      floatx4 w4 = *(const floatx4*)&w2l[s * 256 + lane * 4];
      #pragma unroll
      for (int j = 0; j < 4; ++j) ws[j] += p[s] * w4[j];
    }
    float dot = xs[0]*ws[0] + xs[1]*ws[1] + xs[2]*ws[2] + xs[3]*ws[3];
    #pragma unroll
    for (int off = 32; off > 0; off >>= 1) dot += __shfl_down(dot, off, 64);
    if (lane == 0){
      float bb = 0.f;
      #pragma unroll
      for (int s = 0; s < 12; ++s) bb += p[s] * b2l[s];
      out[b] = dot + bb;
    }
  }
}

extern "C" void kernel_launch(void* const* d_in, const int* in_sizes, int n_in,
                              void* d_out, int out_size, void* d_ws, size_t ws_size,
                              hipStream_t stream){
  const float* treat = (const float*)d_in[0];
  const float* feat  = (const float*)d_in[1];
  const float* W0    = (const float*)d_in[2];
  const float* b0    = (const float*)d_in[3];
  const float* W1    = (const float*)d_in[4];
  const float* b1    = (const float*)d_in[5];
  const float* W2    = (const float*)d_in[6];
  const float* b2    = (const float*)d_in[7];

  char* ws = (char*)d_ws;
  _Float16* Wp0 = (_Float16*)(ws);                     // 1,572,864 B
  _Float16* Wp1 = (_Float16*)(ws + 1572864);           // 1,572,864 B
  _Float16* X1  = (_Float16*)(ws + 3145728);           // 16,777,216 B
  _Float16* X2  = (_Float16*)(ws + 19922944);          // 16,777,216 B
  float* out = (float*)d_out;

  pack_w_kernel<<<192, 256, 0, stream>>>(W0, W1, Wp0, Wp1);
  layer_kernel<true ><<<256, 512, 0, stream>>>((const void*)feat, treat, Wp0, b0, X1);
  layer_kernel<false><<<256, 512, 0, stream>>>((const void*)X1,  treat, Wp1, b1, X2);
  final_kernel<<<2048, 256, 0, stream>>>(X2, treat, W2, b2, out);
}